// Round 1
// baseline (423.698 us; speedup 1.0000x reference)
//
#include <hip/hip_runtime.h>
#include <hip/hip_bf16.h>

// Problem dims (fixed by reference setup_inputs)
#define B_  4
#define L_  4096
#define H_  1024
#define N_  64
#define LN_EPS 1e-5f
#define CH 32          // scan chunk length (steps per LDS reduce)

// ---------------------------------------------------------------------------
// k_prep: Lambda = -exp(LR) + i*exp(LI); a = exp(Lambda);
//         C = (CR + i*CI) * (exp(Lambda)-1)/Lambda   -> Crr/Cii [H][N]
// ---------------------------------------------------------------------------
__global__ __launch_bounds__(256) void k_prep(
    const float* __restrict__ LR, const float* __restrict__ LI,
    const float* __restrict__ CR, const float* __restrict__ CI,
    float* __restrict__ Are, float* __restrict__ Aim,
    float* __restrict__ Crr, float* __restrict__ Cii)
{
    int idx = blockIdx.x * 256 + threadIdx.x;   // 0 .. H*N-1
    int n = idx & (N_ - 1);
    float lr = -expf(LR[n]);      // Re(Lambda) < 0
    float li =  expf(LI[n]);      // Im(Lambda)
    float er = expf(lr);
    float Er = er * cosf(li);
    float Ei = er * sinf(li);
    // w = (E-1)/Lambda
    float nr = Er - 1.0f, ni = Ei;
    float m2 = lr * lr + li * li;
    float inv = 1.0f / m2;
    float wr = (nr * lr + ni * li) * inv;
    float wi = (ni * lr - nr * li) * inv;
    float cr = CR[idx], ci = CI[idx];
    Crr[idx] = cr * wr - ci * wi;
    Cii[idx] = cr * wi + ci * wr;
    if (idx < N_) { Are[idx] = Er; Aim[idx] = Ei; }
}

// ---------------------------------------------------------------------------
// k_stats: per (b,l) row of H=1024: mean and rstd
// ---------------------------------------------------------------------------
__global__ __launch_bounds__(256) void k_stats(
    const float* __restrict__ x, float2* __restrict__ stats)
{
    int row = blockIdx.x;                      // b*L + l
    const float4* xr = (const float4*)(x + (size_t)row * H_);
    float4 v = xr[threadIdx.x];
    float s1 = v.x + v.y + v.z + v.w;
    float s2 = v.x * v.x + v.y * v.y + v.z * v.z + v.w * v.w;
    for (int off = 32; off; off >>= 1) {
        s1 += __shfl_down(s1, off, 64);
        s2 += __shfl_down(s2, off, 64);
    }
    __shared__ float a1[4], a2[4];
    int w = threadIdx.x >> 6, lane = threadIdx.x & 63;
    if (lane == 0) { a1[w] = s1; a2[w] = s2; }
    __syncthreads();
    if (threadIdx.x == 0) {
        float t1 = a1[0] + a1[1] + a1[2] + a1[3];
        float t2 = a2[0] + a2[1] + a2[2] + a2[3];
        float mu  = t1 * (1.0f / H_);
        float var = t2 * (1.0f / H_) - mu * mu;
        stats[row] = make_float2(mu, rsqrtf(var + LN_EPS));
    }
}

// ---------------------------------------------------------------------------
// k_norm_t: xn_t[b,h,l] = LN(x[b,l,h]) via 64x64 LDS tile transpose
// grid: (H/64, L/64, B), block 256
// ---------------------------------------------------------------------------
__global__ __launch_bounds__(256) void k_norm_t(
    const float* __restrict__ x, const float2* __restrict__ stats,
    const float* __restrict__ gamma, const float* __restrict__ beta,
    float* __restrict__ xt)
{
    __shared__ float tile[64][65];
    int h0 = blockIdx.x * 64, l0 = blockIdx.y * 64, b = blockIdx.z;
    int tx = threadIdx.x & 63;
    int ty = threadIdx.x >> 6;
    float g  = gamma[h0 + tx];
    float be = beta[h0 + tx];
    #pragma unroll
    for (int r = 0; r < 16; ++r) {
        int ly = r * 4 + ty;
        float2 st = stats[b * L_ + l0 + ly];
        float v = x[((size_t)b * L_ + (l0 + ly)) * H_ + h0 + tx];
        tile[ly][tx] = (v - st.x) * st.y * g + be;
    }
    __syncthreads();
    #pragma unroll
    for (int r = 0; r < 16; ++r) {
        int hy = r * 4 + ty;
        xt[((size_t)(b * H_ + h0 + hy)) * L_ + l0 + tx] = tile[tx][hy];
    }
}

// ---------------------------------------------------------------------------
// k_scan: one wave per (b,h); lane = mode n. In-place xt -> y_t.
//   s = a*s + u ;  y = Re(sum_n C_n * s_n) + D*u
// grid: B*H/4 blocks of 256 (4 independent waves per block)
// ---------------------------------------------------------------------------
__global__ __launch_bounds__(256) void k_scan(
    float* __restrict__ xt,
    const float* __restrict__ Are, const float* __restrict__ Aim,
    const float* __restrict__ Crr, const float* __restrict__ Cii,
    const float* __restrict__ D)
{
    __shared__ float red[4][CH * 65];
    int lane = threadIdx.x & 63;
    int w    = threadIdx.x >> 6;
    int gw   = blockIdx.x * 4 + w;        // b*H + h
    int h    = gw & (H_ - 1);

    float are = Are[lane], aim = Aim[lane];
    float Cr  = Crr[h * N_ + lane], Ci = Cii[h * N_ + lane];
    float Dh  = D[h];
    float* row = xt + (size_t)gw * L_;
    float* rd  = red[w];

    float sre = 0.0f, sim = 0.0f;
    for (int c = 0; c < L_ / CH; ++c) {
        float u = 0.0f;
        if (lane < CH) u = row[c * CH + lane];      // coalesced 128B
        #pragma unroll
        for (int i = 0; i < CH; ++i) {
            float ui  = __shfl(u, i, 64);           // broadcast step input
            float nre = fmaf(are, sre, ui) - aim * sim;
            float nim = fmaf(are, sim, aim * sre);
            sre = nre; sim = nim;
            rd[i * 65 + lane] = Cr * nre - Ci * nim;  // 2-way bank alias: free
        }
        // transpose-reduce: lane (r,hf) sums half-row r, then combine halves
        int r = lane & 31, hf = lane >> 5;
        float acc = 0.0f;
        #pragma unroll
        for (int j = 0; j < 32; ++j) acc += rd[r * 65 + hf * 32 + j];
        acc += __shfl_xor(acc, 32, 64);
        float ur = __shfl(u, r, 64);
        if (lane < 32) row[c * CH + lane] = fmaf(Dh, ur, acc);  // in-place y_t
    }
}

// ---------------------------------------------------------------------------
// k_out: out[b,l,h] = y_t[b,h,l]  (64x64 LDS tile transpose)
// grid: (H/64, L/64, B), block 256
// ---------------------------------------------------------------------------
__global__ __launch_bounds__(256) void k_out(
    const float* __restrict__ yt, float* __restrict__ out)
{
    __shared__ float tile[64][65];
    int h0 = blockIdx.x * 64, l0 = blockIdx.y * 64, b = blockIdx.z;
    int tx = threadIdx.x & 63;
    int ty = threadIdx.x >> 6;
    #pragma unroll
    for (int r = 0; r < 16; ++r) {
        int hy = r * 4 + ty;
        tile[hy][tx] = yt[((size_t)(b * H_ + h0 + hy)) * L_ + l0 + tx];
    }
    __syncthreads();
    #pragma unroll
    for (int r = 0; r < 16; ++r) {
        int ly = r * 4 + ty;
        out[((size_t)b * L_ + (l0 + ly)) * H_ + h0 + tx] = tile[tx][ly];
    }
}

// ---------------------------------------------------------------------------
extern "C" void kernel_launch(void* const* d_in, const int* in_sizes, int n_in,
                              void* d_out, int out_size, void* d_ws, size_t ws_size,
                              hipStream_t stream)
{
    const float* x     = (const float*)d_in[0];
    const float* gamma = (const float*)d_in[1];
    const float* beta  = (const float*)d_in[2];
    const float* LR    = (const float*)d_in[3];
    const float* LI    = (const float*)d_in[4];
    const float* CR    = (const float*)d_in[5];
    const float* CI    = (const float*)d_in[6];
    const float* D     = (const float*)d_in[7];
    float* out = (float*)d_out;

    // workspace layout
    float*  xt  = (float*)d_ws;                         // B*H*L floats (67MB)
    float2* st  = (float2*)(xt + (size_t)B_ * H_ * L_); // B*L float2
    float*  Are = (float*)(st + (size_t)B_ * L_);       // N
    float*  Aim = Are + N_;
    float*  Crr = Aim + N_;                             // H*N
    float*  Cii = Crr + (size_t)H_ * N_;

    k_prep <<<dim3((H_ * N_) / 256), dim3(256), 0, stream>>>(LR, LI, CR, CI, Are, Aim, Crr, Cii);
    k_stats<<<dim3(B_ * L_),         dim3(256), 0, stream>>>(x, st);
    k_norm_t<<<dim3(H_/64, L_/64, B_), dim3(256), 0, stream>>>(x, st, gamma, beta, xt);
    k_scan <<<dim3(B_ * H_ / 4),     dim3(256), 0, stream>>>(xt, Are, Aim, Crr, Cii, D);
    k_out  <<<dim3(H_/64, L_/64, B_), dim3(256), 0, stream>>>(xt, out);
}

// Round 2
// 293.652 us; speedup vs baseline: 1.4429x; 1.4429x over previous
//
#include <hip/hip_runtime.h>
#include <hip/hip_bf16.h>

// Problem dims (fixed by reference setup_inputs)
#define B_  4
#define L_  4096
#define H_  1024
#define N_  64
#define LN_EPS 1e-5f
#define CH  32           // scan chunk length (steps per LDS reduce)
#define NC  (L_ / CH)

// ---------------------------------------------------------------------------
// k_prep: Lambda = -exp(LR) + i*exp(LI); a = exp(Lambda);
//         C = (CR + i*CI) * (exp(Lambda)-1)/Lambda   -> Crr/Cii [H][N]
// ---------------------------------------------------------------------------
__global__ __launch_bounds__(256) void k_prep(
    const float* __restrict__ LR, const float* __restrict__ LI,
    const float* __restrict__ CR, const float* __restrict__ CI,
    float* __restrict__ Are, float* __restrict__ Aim,
    float* __restrict__ Crr, float* __restrict__ Cii)
{
    int idx = blockIdx.x * 256 + threadIdx.x;   // 0 .. H*N-1
    int n = idx & (N_ - 1);
    float lr = -expf(LR[n]);      // Re(Lambda) < 0
    float li =  expf(LI[n]);      // Im(Lambda)
    float er = expf(lr);
    float Er = er * cosf(li);
    float Ei = er * sinf(li);
    // w = (E-1)/Lambda
    float nr = Er - 1.0f, ni = Ei;
    float m2 = lr * lr + li * li;
    float inv = 1.0f / m2;
    float wr = (nr * lr + ni * li) * inv;
    float wi = (ni * lr - nr * li) * inv;
    float cr = CR[idx], ci = CI[idx];
    Crr[idx] = cr * wr - ci * wi;
    Cii[idx] = cr * wi + ci * wr;
    if (idx < N_) { Are[idx] = Er; Aim[idx] = Ei; }
}

// ---------------------------------------------------------------------------
// k_stats: per (b,l) row of H=1024: mean and rstd
// ---------------------------------------------------------------------------
__global__ __launch_bounds__(256) void k_stats(
    const float* __restrict__ x, float2* __restrict__ stats)
{
    int row = blockIdx.x;                      // b*L + l
    const float4* xr = (const float4*)(x + (size_t)row * H_);
    float4 v = xr[threadIdx.x];
    float s1 = v.x + v.y + v.z + v.w;
    float s2 = v.x * v.x + v.y * v.y + v.z * v.z + v.w * v.w;
    for (int off = 32; off; off >>= 1) {
        s1 += __shfl_down(s1, off, 64);
        s2 += __shfl_down(s2, off, 64);
    }
    __shared__ float a1[4], a2[4];
    int w = threadIdx.x >> 6, lane = threadIdx.x & 63;
    if (lane == 0) { a1[w] = s1; a2[w] = s2; }
    __syncthreads();
    if (threadIdx.x == 0) {
        float t1 = a1[0] + a1[1] + a1[2] + a1[3];
        float t2 = a2[0] + a2[1] + a2[2] + a2[3];
        float mu  = t1 * (1.0f / H_);
        float var = t2 * (1.0f / H_) - mu * mu;
        stats[row] = make_float2(mu, rsqrtf(var + LN_EPS));
    }
}

// ---------------------------------------------------------------------------
// k_norm_t: xn_t[b,h,l] = LN(x[b,l,h]) via 64x64 LDS tile transpose
// grid: (H/64, L/64, B), block 256
// ---------------------------------------------------------------------------
__global__ __launch_bounds__(256) void k_norm_t(
    const float* __restrict__ x, const float2* __restrict__ stats,
    const float* __restrict__ gamma, const float* __restrict__ beta,
    float* __restrict__ xt)
{
    __shared__ float tile[64][65];
    int h0 = blockIdx.x * 64, l0 = blockIdx.y * 64, b = blockIdx.z;
    int tx = threadIdx.x & 63;
    int ty = threadIdx.x >> 6;
    float g  = gamma[h0 + tx];
    float be = beta[h0 + tx];
    #pragma unroll
    for (int r = 0; r < 16; ++r) {
        int ly = r * 4 + ty;
        float2 st = stats[b * L_ + l0 + ly];
        float v = x[((size_t)b * L_ + (l0 + ly)) * H_ + h0 + tx];
        tile[ly][tx] = (v - st.x) * st.y * g + be;
    }
    __syncthreads();
    #pragma unroll
    for (int r = 0; r < 16; ++r) {
        int hy = r * 4 + ty;
        xt[((size_t)(b * H_ + h0 + hy)) * L_ + l0 + tx] = tile[tx][hy];
    }
}

// ---------------------------------------------------------------------------
// k_scan: one WAVE per (b,h) row; lane = mode n.  xt -> yt (yt may == xt).
//   s = a*s + u ;  y = Re(sum_n C_n * s_n) + D*u
// u is wave-uniform per step: loaded once per chunk as 8 broadcast float4
// into registers (all lanes hold all 32 u's) -> no per-step DS broadcast.
// Next chunk is software-prefetched. grid: B*H blocks of 64.
// ---------------------------------------------------------------------------
__global__ __launch_bounds__(64) void k_scan(
    const float* __restrict__ xt, float* __restrict__ yt,
    const float* __restrict__ Are, const float* __restrict__ Aim,
    const float* __restrict__ Crr, const float* __restrict__ Cii,
    const float* __restrict__ D)
{
    __shared__ float rd[CH * 65];
    const int lane = threadIdx.x;
    const int gw = blockIdx.x;            // b*H + h
    const int h = gw & (H_ - 1);

    const float are = Are[lane], aim = Aim[lane];
    const float Cr  = Crr[h * N_ + lane];
    const float nCi = -Cii[h * N_ + lane];
    const float Dh  = D[h];

    const float*  urow  = xt + (size_t)gw * L_;
    const float4* urow4 = (const float4*)urow;
    float* orow = yt + (size_t)gw * L_;

    // chunk-0 preload: uniform broadcast (all lanes same addr) + per-lane copy
    float4 uc[8], un[8];
    #pragma unroll
    for (int k = 0; k < 8; ++k) uc[k] = urow4[k];
    float uo = (lane < CH) ? urow[lane] : 0.0f;   // u[step=lane], for D-term
    float uon = 0.0f;

    float sre = 0.0f, sim = 0.0f;
    const int r = lane & 31, hf = lane >> 5;
    const float* rbase = rd + r * 65 + hf * 32;

    for (int c = 0; c < NC; ++c) {
        // prefetch next chunk (hidden under the 32-step compute)
        if (c + 1 < NC) {
            #pragma unroll
            for (int k = 0; k < 8; ++k) un[k] = urow4[(c + 1) * 8 + k];
            uon = (lane < CH) ? urow[(c + 1) * CH + lane] : 0.0f;
        }
        #pragma unroll
        for (int i = 0; i < CH; ++i) {
            const int q = i >> 2, m = i & 3;   // compile-time after unroll
            float ui = (m == 0) ? uc[q].x : (m == 1) ? uc[q].y
                     : (m == 2) ? uc[q].z : uc[q].w;
            float tre = fmaf(are, sre, ui);
            float nre = fmaf(-aim, sim, tre);
            float nim = fmaf(are, sim, aim * sre);
            sre = nre; sim = nim;
            rd[i * 65 + lane] = fmaf(nCi, nim, Cr * nre);  // 2-way alias: free
        }
        __syncthreads();
        // transpose-reduce: lane (r,hf) sums 32 modes of step r (4 partials)
        float a0 = 0.0f, a1 = 0.0f, a2 = 0.0f, a3 = 0.0f;
        #pragma unroll
        for (int j = 0; j < CH; j += 4) {
            a0 += rbase[j];     a1 += rbase[j + 1];
            a2 += rbase[j + 2]; a3 += rbase[j + 3];
        }
        float acc = (a0 + a1) + (a2 + a3);
        acc += __shfl_xor(acc, 32, 64);
        if (lane < CH) orow[c * CH + lane] = fmaf(Dh, uo, acc);
        __syncthreads();
        #pragma unroll
        for (int k = 0; k < 8; ++k) uc[k] = un[k];
        uo = uon;
    }
}

// ---------------------------------------------------------------------------
// k_out: out[b,l,h] = y_t[b,h,l]  (64x64 LDS tile transpose)
// grid: (H/64, L/64, B), block 256
// ---------------------------------------------------------------------------
__global__ __launch_bounds__(256) void k_out(
    const float* __restrict__ yt, float* __restrict__ out)
{
    __shared__ float tile[64][65];
    int h0 = blockIdx.x * 64, l0 = blockIdx.y * 64, b = blockIdx.z;
    int tx = threadIdx.x & 63;
    int ty = threadIdx.x >> 6;
    #pragma unroll
    for (int r = 0; r < 16; ++r) {
        int hy = r * 4 + ty;
        tile[hy][tx] = yt[((size_t)(b * H_ + h0 + hy)) * L_ + l0 + tx];
    }
    __syncthreads();
    #pragma unroll
    for (int r = 0; r < 16; ++r) {
        int ly = r * 4 + ty;
        out[((size_t)b * L_ + (l0 + ly)) * H_ + h0 + tx] = tile[tx][ly];
    }
}

// ---------------------------------------------------------------------------
extern "C" void kernel_launch(void* const* d_in, const int* in_sizes, int n_in,
                              void* d_out, int out_size, void* d_ws, size_t ws_size,
                              hipStream_t stream)
{
    const float* x     = (const float*)d_in[0];
    const float* gamma = (const float*)d_in[1];
    const float* beta  = (const float*)d_in[2];
    const float* LR    = (const float*)d_in[3];
    const float* LI    = (const float*)d_in[4];
    const float* CR    = (const float*)d_in[5];
    const float* CI    = (const float*)d_in[6];
    const float* D     = (const float*)d_in[7];
    float* out = (float*)d_out;

    const size_t BHL  = (size_t)B_ * H_ * L_;
    const size_t tailElems = 2 * (size_t)B_ * L_ + 2 * N_ + 2 * (size_t)H_ * N_;
    const bool big = ws_size >= (2 * BHL + tailElems) * sizeof(float);

    // workspace layout: xt [, yt], stats, Are, Aim, Crr, Cii
    float* xt = (float*)d_ws;                         // B*H*L floats
    float* yt = big ? xt + BHL : xt;                  // out-of-place if room
    float* tail = big ? yt + BHL : xt + BHL;
    float2* st  = (float2*)tail;                      // B*L float2
    float*  Are = (float*)(st + (size_t)B_ * L_);     // N
    float*  Aim = Are + N_;
    float*  Crr = Aim + N_;                           // H*N
    float*  Cii = Crr + (size_t)H_ * N_;

    k_prep <<<dim3((H_ * N_) / 256), dim3(256), 0, stream>>>(LR, LI, CR, CI, Are, Aim, Crr, Cii);
    k_stats<<<dim3(B_ * L_),         dim3(256), 0, stream>>>(x, st);
    k_norm_t<<<dim3(H_/64, L_/64, B_), dim3(256), 0, stream>>>(x, st, gamma, beta, xt);
    k_scan <<<dim3(B_ * H_),         dim3(64),  0, stream>>>(xt, yt, Are, Aim, Crr, Cii, D);
    k_out  <<<dim3(H_/64, L_/64, B_), dim3(256), 0, stream>>>(yt, out);
}